// Round 6
// baseline (484.596 us; speedup 1.0000x reference)
//
#include <hip/hip_runtime.h>

// BMM_S8T_S8N_F16T: out[b,m,n] = fp16(alpha * sum_k A[b,m,k]*B[b,n,k])
// A: (B,M,K) int32 (int8-range), B: (B,N,K) int32, out: float. B=64, M=N=1024, K=128.
//
// Roofline: 263 MB write + 67 MB read => ~53 us @6.3 TB/s.
// R2-R5 history: barriered 128x128-tile structure plateaus at ~115 us no
//   matter what happens inside the phases (float4 stores neutral, pre/post
//   barrier prefetch neutral). All 8 waves/CU drain at the same
//   s_waitcnt vmcnt(0); s_barrier each iter -> CU idles. Restructure.
// R6: ZERO barriers. Wave-private pipeline:
//   - A rows staged once; wave pair (same wm) both write the shared region
//     with IDENTICAL bytes (benign dup) -> each wave reads only data it
//     wrote itself; lgkmcnt ordering suffices, no barrier.
//   - B tile staged per-iteration into a PER-WAVE private region (waves at
//     different ni cannot interfere). 2x B reads, L2-absorbed.
//   Waves fully self-paced; load-waits of one wave overlap compute/store of
//   the other wave on the same SIMD. LDS 18+36=54 KB -> 2 blocks/CU.

#define Mdim 1024
#define Ndim 1024
#define Kdim 128
#define TILE 128
#define LDS_STRIDE 144  // 128B row + 16B pad; 16B-aligned, bank-balanced b128 reads
#define REGION (64 * LDS_STRIDE)

using int32x4 = __attribute__((ext_vector_type(4))) int;
using floatx4 = __attribute__((ext_vector_type(4))) float;

__device__ __forceinline__ unsigned pack8(int32x4 v) {
    return (unsigned)(v.x & 255) | ((unsigned)(v.y & 255) << 8)
         | ((unsigned)(v.z & 255) << 16) | ((unsigned)(v.w & 255) << 24);
}

// Stage a 64-row x 128-k int32 tile (K-contiguous) -> packed int8 LDS region.
// Per lane: 32 chunks of 16B. Coalesced: lanes 16B-contiguous per instr.
__device__ __forceinline__ void stage64(const int* __restrict__ src,
                                        unsigned char* __restrict__ dst,
                                        int lane) {
#pragma unroll
    for (int j = 0; j < 32; ++j) {
        const int c    = lane + 64 * j;
        const int row  = c >> 5;
        const int colb = (c & 31) * 4;
        const int32x4 v = *(const int32x4*)(src + (size_t)row * Kdim + colb);
        *(unsigned*)(&dst[row * LDS_STRIDE + colb]) = pack8(v);
    }
}

__global__ __launch_bounds__(256)
void bmm_s8_kernel(const int* __restrict__ A, const int* __restrict__ Bm,
                   const float* __restrict__ alpha_p, float* __restrict__ out)
{
    __shared__ unsigned char As[2 * REGION];  // region r: A rows r*64..r*64+63 (benign dup writes)
    __shared__ unsigned char Bs[4 * REGION];  // region w: wave w's private B tile

    const int t    = threadIdx.x;
    const int lane = t & 63;
    const int wave = t >> 6;
    const int z    = blockIdx.x;   // batch; linear%8 == z%8 -> XCD batch affinity
    const int m0   = blockIdx.y * TILE;

    const int wm = (wave >> 1) * 64;
    const int wn = (wave & 1) * 64;

    const int* __restrict__ Ab = A  + (size_t)z * Mdim * Kdim + (size_t)(m0 + wm) * Kdim;
    const int* __restrict__ Bb = Bm + (size_t)z * Ndim * Kdim;

    unsigned char* __restrict__ Areg = &As[(wave >> 1) * REGION];
    unsigned char* __restrict__ Breg = &Bs[wave * REGION];

    // ---- stage this wave's A rows once (both waves of the pair write
    //      identical bytes; each wave's reads covered by its own writes) ----
    stage64(Ab, Areg, lane);

    const float alpha = alpha_p[0];
    const int lrow = lane & 15;
    const int koff = (lane >> 4) * 16;
    const int cm   = lane & 15;        // D col = m_local
    const int cn   = (lane >> 4) * 4;  // D rows = 4 consecutive n_local
    float* __restrict__ Ob = out + (size_t)z * Mdim * Ndim;

#pragma unroll 1
    for (int ni = 0; ni < 8; ++ni) {
        // ---- stage this wave's private B tile (rows ni*128+wn .. +63) ----
        stage64(Bb + (size_t)(ni * TILE + wn) * Kdim, Breg, lane);

        // ---- MFMA: 64(m) x 64(n) ----
        int32x4 acc[4][4];
#pragma unroll
        for (int mt = 0; mt < 4; ++mt)
#pragma unroll
            for (int nt = 0; nt < 4; ++nt)
                acc[mt][nt] = (int32x4){0, 0, 0, 0};

#pragma unroll
        for (int ks = 0; ks < 2; ++ks) {
            int32x4 af[4], bf[4];
#pragma unroll
            for (int mt = 0; mt < 4; ++mt)
                af[mt] = *(const int32x4*)(&Areg[(mt * 16 + lrow) * LDS_STRIDE + ks * 64 + koff]);
#pragma unroll
            for (int nt = 0; nt < 4; ++nt)
                bf[nt] = *(const int32x4*)(&Breg[(nt * 16 + lrow) * LDS_STRIDE + ks * 64 + koff]);
            // swapped operands: D holds m in cols (lane&15), 4 consecutive n in regs
#pragma unroll
            for (int mt = 0; mt < 4; ++mt)
#pragma unroll
                for (int nt = 0; nt < 4; ++nt)
                    acc[mt][nt] = __builtin_amdgcn_mfma_i32_16x16x64_i8(
                        bf[nt], af[mt], acc[mt][nt], 0, 0, 0);
        }

        // ---- epilogue: float4 stores ----
#pragma unroll
        for (int mt = 0; mt < 4; ++mt) {
            const size_t rowbase = (size_t)(m0 + wm + mt * 16 + cm) * Ndim;
#pragma unroll
            for (int nt = 0; nt < 4; ++nt) {
                const int col = ni * TILE + wn + nt * 16 + cn;
                floatx4 v;
                v.x = alpha * (float)acc[mt][nt][0];
                v.y = alpha * (float)acc[mt][nt][1];
                v.z = alpha * (float)acc[mt][nt][2];
                v.w = alpha * (float)acc[mt][nt][3];
                *(floatx4*)(Ob + rowbase + col) = v;
            }
        }
        // no barrier: Breg is wave-private; next iter's ds_writes ordered
        // against this iter's ds_reads within the wave by lgkmcnt.
    }
}

extern "C" void kernel_launch(void* const* d_in, const int* in_sizes, int n_in,
                              void* d_out, int out_size, void* d_ws, size_t ws_size,
                              hipStream_t stream) {
    const int*   a     = (const int*)d_in[0];
    const int*   b     = (const int*)d_in[1];
    const float* alpha = (const float*)d_in[2];
    float*       out   = (float*)d_out;

    const int batch = in_sizes[0] / (Mdim * Kdim);  // 64
    dim3 grid(batch, Mdim / TILE);                  // (64, 8): linear%8 == z%8
    bmm_s8_kernel<<<grid, 256, 0, stream>>>(a, b, alpha, out);
}